// Round 6
// baseline (271.330 us; speedup 1.0000x reference)
//
#include <hip/hip_runtime.h>

// out = (sum_p cos(w_p * phi_p) + (N - C)) / N,  N = next pow2 >= C.
// Pure memory-bound reduction: 256 MiB read, 4 B write.
//
// R10 model (from R4-R9 ledger): the two arrays total EXACTLY the 256 MiB
// L3 capacity, so steady state keeps exactly one array's worth (134 MB)
// resident (FETCH_SIZE == 134 MB in every variant); the other 134 MB
// streams from HBM at the observed ~1.9 TB/s read rate, and lockstep
// pair consumption makes that the binder: 134/1.9 ~= 63-72 us == R4.
// Scope bits probed (R9): sys-scope nt ~= normal path. Depth, layout,
// decoupling, full-allocation all null-or-negative.
// Lever: make L3 demand FIT. phi split per-block: first half PLAIN
// (allocates -> resident), second half NT (no-allocate -> HBM stream);
// w always PLAIN (pins residency). L3 demand = 134 + 67 = 201 MB < 256
// -> stable; HBM stream = 67 MB only.
// Discriminator: (a) HBM-rate-bound -> ~38-45 us kernel, FETCH ~67 MB,
// total ~215-225. (b) shared-path cap ~3.7 TB/s -> ~72-77 us unchanged,
// FETCH drops anyway -> declare roofline next round.
// NOTE: timed dur_us carries ~170 us of harness restore/poison floor.

#define RBLOCKS 2048   // 8 blocks/CU; span = n4/2048 = 4096 v4f per array
#define RTHREADS 256

typedef float v4f __attribute__((ext_vector_type(4)));

__device__ __forceinline__ float cos4(v4f a, v4f b) {
    return __cosf(a.x * b.x) + __cosf(a.y * b.y)
         + __cosf(a.z * b.z) + __cosf(a.w * b.w);
}

__global__ __launch_bounds__(RTHREADS) void qs_partial_kernel(
    const float* __restrict__ phi, const float* __restrict__ w,
    float* __restrict__ partials, int n4, int n, int cut4) {
    const v4f* __restrict__ p4 = (const v4f*)phi;
    const v4f* __restrict__ w4 = (const v4f*)w;

    const int span  = (n4 + (int)gridDim.x - 1) / (int)gridDim.x;
    const int start = (int)blockIdx.x * span;
    const int lim   = (start + span < n4) ? (start + span) : n4;

    // block-uniform policy: spans in the first half of the index space
    // load phi PLAIN (allocate in L3 -> resident next iteration); spans
    // in the second half load phi NT (no-allocate -> pure HBM stream).
    const bool phi_plain = (lim <= cut4);

    float acc0 = 0.0f, acc1 = 0.0f, acc2 = 0.0f, acc3 = 0.0f;
    int i = start + (int)threadIdx.x;

    if (phi_plain) {
        for (; i + 3 * RTHREADS < lim; i += 4 * RTHREADS) {
            v4f a0 = p4[i];
            v4f a1 = p4[i + RTHREADS];
            v4f a2 = p4[i + 2 * RTHREADS];
            v4f a3 = p4[i + 3 * RTHREADS];
            v4f b0 = w4[i];
            v4f b1 = w4[i + RTHREADS];
            v4f b2 = w4[i + 2 * RTHREADS];
            v4f b3 = w4[i + 3 * RTHREADS];
            acc0 += cos4(a0, b0);
            acc1 += cos4(a1, b1);
            acc2 += cos4(a2, b2);
            acc3 += cos4(a3, b3);
        }
    } else {
        for (; i + 3 * RTHREADS < lim; i += 4 * RTHREADS) {
            v4f a0 = __builtin_nontemporal_load(p4 + i);
            v4f a1 = __builtin_nontemporal_load(p4 + i + RTHREADS);
            v4f a2 = __builtin_nontemporal_load(p4 + i + 2 * RTHREADS);
            v4f a3 = __builtin_nontemporal_load(p4 + i + 3 * RTHREADS);
            v4f b0 = w4[i];
            v4f b1 = w4[i + RTHREADS];
            v4f b2 = w4[i + 2 * RTHREADS];
            v4f b3 = w4[i + 3 * RTHREADS];
            acc0 += cos4(a0, b0);
            acc1 += cos4(a1, b1);
            acc2 += cos4(a2, b2);
            acc3 += cos4(a3, b3);
        }
    }
    // remainder float4s (1-deep, plain — tiny)
    for (; i < lim; i += RTHREADS) {
        acc0 += cos4(p4[i], w4[i]);
    }
    // scalar tail (n not divisible by 4) — single thread, tiny
    if (blockIdx.x == 0 && threadIdx.x == 0) {
        for (int j = n4 * 4; j < n; ++j) acc0 += __cosf(phi[j] * w[j]);
    }

    float acc = (acc0 + acc1) + (acc2 + acc3);

    // wave-64 shuffle reduce
    #pragma unroll
    for (int off = 32; off > 0; off >>= 1)
        acc += __shfl_down(acc, off, 64);

    __shared__ float smem[RTHREADS / 64];
    int lane = threadIdx.x & 63;
    int wid  = threadIdx.x >> 6;
    if (lane == 0) smem[wid] = acc;
    __syncthreads();
    if (threadIdx.x == 0) {
        float t = 0.0f;
        #pragma unroll
        for (int k = 0; k < RTHREADS / 64; ++k) t += smem[k];
        partials[blockIdx.x] = t;
    }
}

__global__ __launch_bounds__(1024) void qs_final_kernel(
    const float* __restrict__ partials, float* __restrict__ out,
    int nb, float addend, float inv_n) {
    float acc = 0.0f;
    for (int i = threadIdx.x; i < nb; i += blockDim.x) acc += partials[i];

    #pragma unroll
    for (int off = 32; off > 0; off >>= 1)
        acc += __shfl_down(acc, off, 64);

    __shared__ float smem[1024 / 64];
    int lane = threadIdx.x & 63;
    int wid  = threadIdx.x >> 6;
    if (lane == 0) smem[wid] = acc;
    __syncthreads();
    if (threadIdx.x == 0) {
        float t = 0.0f;
        #pragma unroll
        for (int k = 0; k < 1024 / 64; ++k) t += smem[k];
        out[0] = (t + addend) * inv_n;  // overwrites poisoned d_out every call
    }
}

extern "C" void kernel_launch(void* const* d_in, const int* in_sizes, int n_in,
                              void* d_out, int out_size, void* d_ws, size_t ws_size,
                              hipStream_t stream) {
    const float* phi = (const float*)d_in[0];
    const float* w   = (const float*)d_in[1];
    float* out       = (float*)d_out;
    float* partials  = (float*)d_ws;

    int n  = in_sizes[0];
    int n4 = n >> 2;
    int cut4 = n4 >> 1;  // first half of v4f index space -> plain phi

    // N = 2^ceil(log2(n))
    long long N = 1;
    while (N < (long long)n) N <<= 1;
    float addend = (float)(N - (long long)n);
    float inv_n  = 1.0f / (float)N;

    qs_partial_kernel<<<RBLOCKS, RTHREADS, 0, stream>>>(
        phi, w, partials, n4, n, cut4);
    qs_final_kernel<<<1, 1024, 0, stream>>>(
        partials, out, RBLOCKS, addend, inv_n);
}

// Round 7
// 245.640 us; speedup vs baseline: 1.1046x; 1.1046x over previous
//
#include <hip/hip_runtime.h>

// out = (sum_p cos(w_p * phi_p) + (N - C)) / N,  N = next pow2 >= C.
// Pure memory-bound reduction: 256 MiB read, 4 B write.
//
// R11: FINAL revert to the session-best R4 structure (246.1 us total).
// Ledger of everything tried and measured (qs_partial effective read BW):
//   R4  nt+nt, spans, 4-deep, 4 accs            3.7 TB/s  <- best
//   R5  nt phi + global_load_lds w (decoupled)  3.48
//   R6  nt+plain, compact grid-stride           3.46
//   R7  plain+plain                             2.55 (L2 alloc churn)
//   R9  sys-scope (sc0 sc1 nt) probe            ~= normal path
//   R10 half-plain phi (residency steering)     3.0, FETCH unchanged
// Invariant: FETCH_SIZE == exactly 134 MB (half of demand) under EVERY
// request-side policy -> the 256 MiB MALL is a memory-side cache whose
// allocation ignores nt/scope bits; residency cannot be steered.
// Ceiling arithmetic: 268 MB mandatory reads / ~3.7 TB/s demonstrated
// read-path max = ~72 us = where this kernel sits. Writes (6.9 TB/s
// fill) are NOT evidence of read capability; no read measurement on
// this chip exceeds ~3.7. Depth, layout, decoupling, allocation policy,
// scope bits: all null-or-negative. Read roofline reached.
// NOTE: timed dur_us carries ~170 us of harness restore/poison floor.

#define RBLOCKS 2048   // 8 blocks/CU; span = n4/2048 = 4096 v4f per array
#define RTHREADS 256

typedef float v4f __attribute__((ext_vector_type(4)));

__global__ __launch_bounds__(RTHREADS) void qs_partial_kernel(
    const float* __restrict__ phi, const float* __restrict__ w,
    float* __restrict__ partials, int n4, int n) {
    const v4f* __restrict__ p4 = (const v4f*)phi;
    const v4f* __restrict__ w4 = (const v4f*)w;

    // contiguous span per block: DRAM page + XCD-L2 locality
    const int span  = (n4 + (int)gridDim.x - 1) / (int)gridDim.x;
    const int start = (int)blockIdx.x * span;
    const int lim   = (start + span < n4) ? (start + span) : n4;

    float acc0 = 0.0f, acc1 = 0.0f, acc2 = 0.0f, acc3 = 0.0f;
    int i = start + (int)threadIdx.x;

    // 4-deep batch: 8 independent nt 16B loads in flight per lane,
    // 4 separate accumulator chains so vmcnt waits stay fine-grained.
    for (; i + 3 * RTHREADS < lim; i += 4 * RTHREADS) {
        v4f a0 = __builtin_nontemporal_load(p4 + i);
        v4f a1 = __builtin_nontemporal_load(p4 + i + RTHREADS);
        v4f a2 = __builtin_nontemporal_load(p4 + i + 2 * RTHREADS);
        v4f a3 = __builtin_nontemporal_load(p4 + i + 3 * RTHREADS);
        v4f b0 = __builtin_nontemporal_load(w4 + i);
        v4f b1 = __builtin_nontemporal_load(w4 + i + RTHREADS);
        v4f b2 = __builtin_nontemporal_load(w4 + i + 2 * RTHREADS);
        v4f b3 = __builtin_nontemporal_load(w4 + i + 3 * RTHREADS);
        acc0 += __cosf(a0.x * b0.x) + __cosf(a0.y * b0.y)
              + __cosf(a0.z * b0.z) + __cosf(a0.w * b0.w);
        acc1 += __cosf(a1.x * b1.x) + __cosf(a1.y * b1.y)
              + __cosf(a1.z * b1.z) + __cosf(a1.w * b1.w);
        acc2 += __cosf(a2.x * b2.x) + __cosf(a2.y * b2.y)
              + __cosf(a2.z * b2.z) + __cosf(a2.w * b2.w);
        acc3 += __cosf(a3.x * b3.x) + __cosf(a3.y * b3.y)
              + __cosf(a3.z * b3.z) + __cosf(a3.w * b3.w);
    }
    // remainder float4s (1-deep)
    for (; i < lim; i += RTHREADS) {
        v4f a = __builtin_nontemporal_load(p4 + i);
        v4f b = __builtin_nontemporal_load(w4 + i);
        acc0 += __cosf(a.x * b.x) + __cosf(a.y * b.y)
              + __cosf(a.z * b.z) + __cosf(a.w * b.w);
    }
    // scalar tail (n not divisible by 4) — single thread, tiny
    if (blockIdx.x == 0 && threadIdx.x == 0) {
        for (int j = n4 * 4; j < n; ++j) acc0 += __cosf(phi[j] * w[j]);
    }

    float acc = (acc0 + acc1) + (acc2 + acc3);

    // wave-64 shuffle reduce
    #pragma unroll
    for (int off = 32; off > 0; off >>= 1)
        acc += __shfl_down(acc, off, 64);

    __shared__ float smem[RTHREADS / 64];
    int lane = threadIdx.x & 63;
    int wid  = threadIdx.x >> 6;
    if (lane == 0) smem[wid] = acc;
    __syncthreads();
    if (threadIdx.x == 0) {
        float t = 0.0f;
        #pragma unroll
        for (int k = 0; k < RTHREADS / 64; ++k) t += smem[k];
        partials[blockIdx.x] = t;
    }
}

__global__ __launch_bounds__(1024) void qs_final_kernel(
    const float* __restrict__ partials, float* __restrict__ out,
    int nb, float addend, float inv_n) {
    float acc = 0.0f;
    for (int i = threadIdx.x; i < nb; i += blockDim.x) acc += partials[i];

    #pragma unroll
    for (int off = 32; off > 0; off >>= 1)
        acc += __shfl_down(acc, off, 64);

    __shared__ float smem[1024 / 64];
    int lane = threadIdx.x & 63;
    int wid  = threadIdx.x >> 6;
    if (lane == 0) smem[wid] = acc;
    __syncthreads();
    if (threadIdx.x == 0) {
        float t = 0.0f;
        #pragma unroll
        for (int k = 0; k < 1024 / 64; ++k) t += smem[k];
        out[0] = (t + addend) * inv_n;  // overwrites poisoned d_out every call
    }
}

extern "C" void kernel_launch(void* const* d_in, const int* in_sizes, int n_in,
                              void* d_out, int out_size, void* d_ws, size_t ws_size,
                              hipStream_t stream) {
    const float* phi = (const float*)d_in[0];
    const float* w   = (const float*)d_in[1];
    float* out       = (float*)d_out;
    float* partials  = (float*)d_ws;

    int n  = in_sizes[0];
    int n4 = n >> 2;

    // N = 2^ceil(log2(n))
    long long N = 1;
    while (N < (long long)n) N <<= 1;
    float addend = (float)(N - (long long)n);
    float inv_n  = 1.0f / (float)N;

    qs_partial_kernel<<<RBLOCKS, RTHREADS, 0, stream>>>(phi, w, partials, n4, n);
    qs_final_kernel<<<1, 1024, 0, stream>>>(partials, out, RBLOCKS, addend, inv_n);
}